// Round 8
// baseline (342.436 us; speedup 1.0000x reference)
//
#include <hip/hip_runtime.h>
#include <hip/hip_fp16.h>
#include <math.h>

#define DIM 768
#define NTOK 1024
#define NBATCH 16
#define BNR (NBATCH * NTOK)   // 16384 rows

typedef _Float16 f16x8 __attribute__((ext_vector_type(8)));
typedef float f32x4 __attribute__((ext_vector_type(4)));

// async global->LDS, 16B per lane, LDS dest = wave-uniform base + lane*16
__device__ __forceinline__ void gl2lds16(const void* g, void* l) {
    __builtin_amdgcn_global_load_lds(
        (const __attribute__((address_space(1))) void*)g,
        (__attribute__((address_space(3))) void*)l, 16, 0, 0);
}

// branch-free exact-gelu: erf via Abramowitz-Stegun 7.1.26 (|abs err| <= 1.5e-7)
__device__ __forceinline__ float gelu_fast(float z) {
    const float s = z * 0.70710678118654752f;
    const float ax = fabsf(s);
    const float t = __builtin_amdgcn_rcpf(1.0f + 0.3275911f * ax);
    const float poly = t * (0.254829592f + t * (-0.284496736f +
                       t * (1.421413741f + t * (-1.453152027f + t * 1.061405429f))));
    const float e = __expf(-ax * ax);
    float erfv = 1.0f - poly * e;
    erfv = copysignf(erfv, s);
    return 0.5f * z * (1.0f + erfv);
}

// avg over tokens, split 8-way over the token axis for parallelism
__global__ __launch_bounds__(256) void avg_kernel(const float* __restrict__ x,
                                                  float* __restrict__ avgx) {
    const int d = blockIdx.x * 256 + threadIdx.x;
    const int b = blockIdx.y;
    const int n0 = blockIdx.z * 128;
    const float* xp = x + (size_t)b * NTOK * DIM + (size_t)n0 * DIM + d;
    float s = 0.0f;
    for (int n = 0; n < 128; ++n) s += xp[(size_t)n * DIM];
    atomicAdd(&avgx[b * DIM + d], s * (1.0f / NTOK));
}

// s1[col] = sum over k of w1[768+k][col]  (rank-1 term for the (x+m) half of L1)
__global__ __launch_bounds__(256) void colsum_w1b(const float* __restrict__ w1,
                                                  float* __restrict__ s1) {
    const int col = blockIdx.x * 256 + threadIdx.x;   // 3 col-blocks
    const int r0 = 768 + blockIdx.y * 64;             // 12 row-chunks
    float s = 0.0f;
    #pragma unroll 8
    for (int r = 0; r < 64; ++r) s += w1[(size_t)(r0 + r) * 768 + col];
    atomicAdd(&s1[col], s);
}

// LN -> sigmoid -> A = avg_x*sig (fp16), plus xh = fp16(x); wave-per-row, no barriers.
// sq computed from fp16-rounded A (consistent with what dist16 consumes).
__global__ __launch_bounds__(256) void ln_sig_kernel(
    const float* __restrict__ x, const float* __restrict__ gamma,
    const float* __restrict__ beta, const float* __restrict__ avgx,
    __half* __restrict__ Ah, __half* __restrict__ xh, float* __restrict__ sq)
{
    const int wv = threadIdx.x >> 6, lane = threadIdx.x & 63;
    const int row = blockIdx.x * 4 + wv;
    const int b = row >> 10;
    const float* xr = x + (size_t)row * DIM;
    float4 v[3];
    #pragma unroll
    for (int i = 0; i < 3; ++i) v[i] = *(const float4*)&xr[i * 256 + lane * 4];
    float s = v[0].x + v[0].y + v[0].z + v[0].w
            + v[1].x + v[1].y + v[1].z + v[1].w
            + v[2].x + v[2].y + v[2].z + v[2].w;
    #pragma unroll
    for (int o = 32; o > 0; o >>= 1) s += __shfl_xor(s, o, 64);
    const float mu = s * (1.0f / DIM);
    float ss = 0.0f;
    #pragma unroll
    for (int i = 0; i < 3; ++i) {
        const float dx0 = v[i].x - mu, dx1 = v[i].y - mu, dx2 = v[i].z - mu, dx3 = v[i].w - mu;
        ss += dx0 * dx0 + dx1 * dx1 + dx2 * dx2 + dx3 * dx3;
    }
    #pragma unroll
    for (int o = 32; o > 0; o >>= 1) ss += __shfl_xor(ss, o, 64);
    const float rstd = rsqrtf(ss * (1.0f / DIM) + 1e-5f);
    float qs = 0.0f;
    #pragma unroll
    for (int i = 0; i < 3; ++i) {
        const int d0 = i * 256 + lane * 4;
        const float4 g4 = *(const float4*)&gamma[d0];
        const float4 b4 = *(const float4*)&beta[d0];
        const float4 a4 = *(const float4*)&avgx[b * DIM + d0];
        ushort4 pa, px;
        const float xv[4] = {v[i].x, v[i].y, v[i].z, v[i].w};
        const float gv[4] = {g4.x, g4.y, g4.z, g4.w};
        const float bv[4] = {b4.x, b4.y, b4.z, b4.w};
        const float av[4] = {a4.x, a4.y, a4.z, a4.w};
        unsigned short pav[4], pxv[4];
        #pragma unroll
        for (int j = 0; j < 4; ++j) {
            const float ln = (xv[j] - mu) * rstd * gv[j] + bv[j];
            const float sg = 1.0f / (1.0f + expf(-ln));
            const float a = av[j] * sg;
            const __half h = __float2half(a);
            const float ar = __half2float(h);
            qs += ar * ar;
            pav[j] = __half_as_ushort(h);
            pxv[j] = __half_as_ushort(__float2half(xv[j]));
        }
        pa.x = pav[0]; pa.y = pav[1]; pa.z = pav[2]; pa.w = pav[3];
        px.x = pxv[0]; px.y = pxv[1]; px.z = pxv[2]; px.w = pxv[3];
        *(ushort4*)&Ah[(size_t)row * DIM + d0] = pa;
        *(ushort4*)&xh[(size_t)row * DIM + d0] = px;
    }
    #pragma unroll
    for (int o = 32; o > 0; o >>= 1) qs += __shfl_xor(qs, o, 64);
    if (lane == 0) sq[row] = qs;
}

// fp32 [K][N] -> fp16 [N][K] tiled transpose (shared body)
__device__ __forceinline__ void wconv_body(const float* __restrict__ w,
                                           __half* __restrict__ wT, int K, int N,
                                           int bx, int by)
{
    __shared__ float t[64][65];
    const int k0 = by * 64, n0 = bx * 64;
    const int tid = threadIdx.x;
    const int r = tid >> 4, c4 = (tid & 15) * 4;
    #pragma unroll
    for (int p = 0; p < 4; ++p) {
        const int rr = p * 16 + r;
        const float4 v = *(const float4*)&w[(size_t)(k0 + rr) * N + n0 + c4];
        t[rr][c4] = v.x; t[rr][c4 + 1] = v.y; t[rr][c4 + 2] = v.z; t[rr][c4 + 3] = v.w;
    }
    __syncthreads();
    #pragma unroll
    for (int p = 0; p < 4; ++p) {
        const int nn = p * 16 + r;
        ushort4 pk;
        pk.x = __half_as_ushort(__float2half(t[c4 + 0][nn]));
        pk.y = __half_as_ushort(__float2half(t[c4 + 1][nn]));
        pk.z = __half_as_ushort(__float2half(t[c4 + 2][nn]));
        pk.w = __half_as_ushort(__float2half(t[c4 + 3][nn]));
        *(ushort4*)&wT[(size_t)(n0 + nn) * K + k0 + c4] = pk;
    }
}

__global__ __launch_bounds__(256) void wconv(const float* __restrict__ w,
                                             __half* __restrict__ wT, int K, int N)
{
    wconv_body(w, wT, K, N, blockIdx.x, blockIdx.y);
}

// batched 768x768 transposes for w2/w3/w4 (one dispatch instead of three)
__global__ __launch_bounds__(256) void wconv3(const float* __restrict__ w2,
                                              const float* __restrict__ w3,
                                              const float* __restrict__ w4,
                                              __half* __restrict__ t2,
                                              __half* __restrict__ t3,
                                              __half* __restrict__ t4)
{
    const float* w = (blockIdx.z == 0) ? w2 : (blockIdx.z == 1) ? w3 : w4;
    __half* wT = (blockIdx.z == 0) ? t2 : (blockIdx.z == 1) ? t3 : t4;
    wconv_body(w, wT, 768, 768, blockIdx.x, blockIdx.y);
}

// ---- MFMA fp16 GEMM, 128x128 tile, BK=32, 8 waves, 3-buffer counted-vmcnt ring ----
// Depth-2 pipeline (fix for the diagnosed stall: depth-1 prefetch gave each tile only
// ~0.8 compute-phases vs ~600-900cy load latency; waves convoy at the per-iter drain).
// Per iter: s_waitcnt vmcnt(2) [own 2 tile-t loads retired; tile t+1's 2 loads STAY
// IN FLIGHT across the barrier] -> raw s_barrier [after it, ALL waves' tile-t loads
// are in LDS: each waited before arriving] -> stage(t+2) issued FIRST (gets ~2 full
// compute phases) -> ds_reads(buf t%3) -> 8 MFMA. No sched_barrier pins (R1's VGPR
// blowup cause). WAR safe: a wave past iter-t's barrier already consumed its t-1
// frags (MFMAs forced the lgkm waits), so overwriting buf[(t-1)%3]==buf[(t+2)%3] is
// race-free. NT divisible by 3 (24,48) keeps %3 static under unroll-3.
// LDS swizzle: logical (row,koct) at halves row*32 + (koct^((row>>1)&3))*8 ->
//   2-way bank aliasing = free; verified SQ_LDS_BANK_CONFLICT 4.72M -> 0.
// EPI 0: m1=gelu(z + m[row]*s1[col])->fp16 ; 1: h3=m1h*x*gelu(z)->fp16 ;
// EPI 2: h4=x*gelu(z)->fp16 ; 3: out=gelu(z)->fp32
template<int K, bool CAT, int EPI>
__global__ __launch_bounds__(512, 6) void gemm16(
    const __half* __restrict__ A0, const __half* __restrict__ A1,
    const __half* __restrict__ BT, const float* __restrict__ bias,
    const float* __restrict__ xin, const __half* __restrict__ m1h,
    const float* __restrict__ mv, const float* __restrict__ sv,
    __half* __restrict__ outH, float* __restrict__ outF)
{
    __shared__ _Float16 As[3][128 * 32];
    __shared__ _Float16 Bs[3][128 * 32];
    const int tid = threadIdx.x;
    const int w = tid >> 6, lane = tid & 63;
    const int wu = __builtin_amdgcn_readfirstlane(w);
    const int wr = w >> 2, wc = w & 3;          // wave -> 64-row x 32-col quadrant
    const int R0 = blockIdx.x * 128, J0 = blockIdx.y * 128;
    constexpr int rs = CAT ? DIM : K;           // A row stride (halves)
    const int srow = lane >> 2;                 // staging row within 16
    const int sk8 = (((lane & 3) ^ ((lane >> 3) & 3))) * 8;  // swizzled k-offset (halves)
    const int fx = ((lane >> 4) ^ ((lane >> 1) & 3)) * 8;    // frag-read swizzled oct offset
    constexpr int NT = K / 32;
    static_assert(NT % 3 == 0, "ring needs NT % 3 == 0");

    f32x4 acc[4][2];
    #pragma unroll
    for (int mt = 0; mt < 4; ++mt)
        #pragma unroll
        for (int nt = 0; nt < 2; ++nt) {
            f32x4 z = {0.0f, 0.0f, 0.0f, 0.0f};
            acc[mt][nt] = z;
        }

    auto stage = [&](int buf, int k0) {
        const __half* Ab = (CAT && k0 >= DIM) ? (A1 + (k0 - DIM)) : (A0 + k0);
        // 8 waves x (1 A-slab + 1 B-slab) of 16 rows each covers 128+128 rows
        gl2lds16(Ab + (size_t)(R0 + w * 16 + srow) * rs + sk8, &As[buf][(wu * 16) * 32]);
        gl2lds16(BT + (size_t)(J0 + w * 16 + srow) * K + k0 + sk8, &Bs[buf][(wu * 16) * 32]);
    };

    stage(0, 0);
    stage(1, 32);
    #pragma unroll 3
    for (int kt = 0; kt < NT; ++kt) {
        const int cur = kt % 3;
        if (kt == NT - 1) { asm volatile("s_waitcnt vmcnt(0)" ::: "memory"); }
        else              { asm volatile("s_waitcnt vmcnt(2)" ::: "memory"); }
        __builtin_amdgcn_s_barrier();
        if (kt + 2 < NT) stage((kt + 2) % 3, (kt + 2) * 32);
        f16x8 af[4], bf[2];
        #pragma unroll
        for (int mt = 0; mt < 4; ++mt)
            af[mt] = *(const f16x8*)&As[cur][(wr * 64 + mt * 16 + (lane & 15)) * 32 + fx];
        #pragma unroll
        for (int nt = 0; nt < 2; ++nt)
            bf[nt] = *(const f16x8*)&Bs[cur][(wc * 32 + nt * 16 + (lane & 15)) * 32 + fx];
        #pragma unroll
        for (int mt = 0; mt < 4; ++mt)
            #pragma unroll
            for (int nt = 0; nt < 2; ++nt)
                acc[mt][nt] = __builtin_amdgcn_mfma_f32_16x16x32_f16(af[mt], bf[nt], acc[mt][nt], 0, 0, 0);
    }

    // C/D layout: col = lane&15, row = (lane>>4)*4 + reg
    #pragma unroll
    for (int mt = 0; mt < 4; ++mt) {
        float mrow[4];
        if constexpr (EPI == 0) {
            #pragma unroll
            for (int r = 0; r < 4; ++r)
                mrow[r] = mv[R0 + wr * 64 + mt * 16 + (lane >> 4) * 4 + r];
        }
        #pragma unroll
        for (int nt = 0; nt < 2; ++nt) {
            const int col = J0 + wc * 32 + nt * 16 + (lane & 15);
            const float bv = bias[col];
            float s1c = 0.0f;
            if constexpr (EPI == 0) s1c = sv[col];
            #pragma unroll
            for (int r = 0; r < 4; ++r) {
                const int row = R0 + wr * 64 + mt * 16 + (lane >> 4) * 4 + r;
                const size_t off = (size_t)row * DIM + col;
                if (EPI == 0) {
                    const float g = gelu_fast(acc[mt][nt][r] + bv + mrow[r] * s1c);
                    outH[off] = __float2half(g);
                } else if (EPI == 1) {
                    const float g = gelu_fast(acc[mt][nt][r] + bv);
                    outH[off] = __float2half(__half2float(m1h[off]) * xin[off] * g);
                } else if (EPI == 2) {
                    const float g = gelu_fast(acc[mt][nt][r] + bv);
                    outH[off] = __float2half(xin[off] * g);
                } else {
                    outF[off] = gelu_fast(acc[mt][nt][r] + bv);
                }
            }
        }
    }
}

// dist row-max over UPPER-TRIANGLE tiles only (dist is symmetric): 36 of 64
// 128x128 tiles per batch; off-diagonal tiles feed row-max AND col-max.
// Same 3-buffer counted-vmcnt ring (4 loads/stage -> vmcnt(4) steady).
// atomicMax on positive floats as uints is order-preserving; max commutes with sqrt.
__global__ __launch_bounds__(256, 4) void dist16(const __half* __restrict__ Ah,
                                                 const float* __restrict__ sq,
                                                 float* __restrict__ m)
{
    __shared__ _Float16 As[3][128 * 32];
    __shared__ _Float16 Bs[3][128 * 32];
    const int tid = threadIdx.x;
    const int w = tid >> 6, lane = tid & 63;
    const int wu = __builtin_amdgcn_readfirstlane(w);
    const int wr = w >> 1, wc = w & 1;
    const int base = blockIdx.x * NTOK;
    // decode upper-triangle tile id -> (ty, tz), ty<=tz, 8x8 tile grid
    int t = blockIdx.y, ty = 0;
    while (t >= 8 - ty) { t -= 8 - ty; ++ty; }
    const int tz = ty + t;
    const int I0 = ty * 128, J0 = tz * 128;
    const int srow = lane >> 2;
    const int sk8 = (((lane & 3) ^ ((lane >> 3) & 3))) * 8;
    const int fx = ((lane >> 4) ^ ((lane >> 1) & 3)) * 8;
    constexpr int NT = DIM / 32;
    static_assert(NT % 3 == 0, "ring needs NT % 3 == 0");

    f32x4 acc[4][4];
    #pragma unroll
    for (int mt = 0; mt < 4; ++mt)
        #pragma unroll
        for (int nt = 0; nt < 4; ++nt) {
            f32x4 z = {0.0f, 0.0f, 0.0f, 0.0f};
            acc[mt][nt] = z;
        }

    auto stage = [&](int buf, int k0) {
        #pragma unroll
        for (int i = 0; i < 2; ++i) {
            const int rbase = i * 64 + w * 16;
            const int rbu = i * 64 + wu * 16;
            gl2lds16(Ah + (size_t)(base + I0 + rbase + srow) * DIM + k0 + sk8, &As[buf][rbu * 32]);
            gl2lds16(Ah + (size_t)(base + J0 + rbase + srow) * DIM + k0 + sk8, &Bs[buf][rbu * 32]);
        }
    };

    stage(0, 0);
    stage(1, 32);
    #pragma unroll 3
    for (int kt = 0; kt < NT; ++kt) {
        const int cur = kt % 3;
        if (kt == NT - 1) { asm volatile("s_waitcnt vmcnt(0)" ::: "memory"); }
        else              { asm volatile("s_waitcnt vmcnt(4)" ::: "memory"); }
        __builtin_amdgcn_s_barrier();
        if (kt + 2 < NT) stage((kt + 2) % 3, (kt + 2) * 32);
        f16x8 af[4], bf[4];
        #pragma unroll
        for (int mt = 0; mt < 4; ++mt)
            af[mt] = *(const f16x8*)&As[cur][(wr * 64 + mt * 16 + (lane & 15)) * 32 + fx];
        #pragma unroll
        for (int nt = 0; nt < 4; ++nt)
            bf[nt] = *(const f16x8*)&Bs[cur][(wc * 64 + nt * 16 + (lane & 15)) * 32 + fx];
        #pragma unroll
        for (int mt = 0; mt < 4; ++mt)
            #pragma unroll
            for (int nt = 0; nt < 4; ++nt)
                acc[mt][nt] = __builtin_amdgcn_mfma_f32_16x16x32_f16(af[mt], bf[nt], acc[mt][nt], 0, 0, 0);
    }

    float sqiA[4][4];
    #pragma unroll
    for (int mt = 0; mt < 4; ++mt)
        #pragma unroll
        for (int r = 0; r < 4; ++r)
            sqiA[mt][r] = sq[base + I0 + wr * 64 + mt * 16 + (lane >> 4) * 4 + r];
    float sqjA[4];
    #pragma unroll
    for (int nt = 0; nt < 4; ++nt)
        sqjA[nt] = sq[base + J0 + wc * 64 + nt * 16 + (lane & 15)];

    // row-max -> m[I-rows]
    #pragma unroll
    for (int mt = 0; mt < 4; ++mt) {
        float vmax[4] = {-1e30f, -1e30f, -1e30f, -1e30f};
        #pragma unroll
        for (int nt = 0; nt < 4; ++nt)
            #pragma unroll
            for (int r = 0; r < 4; ++r)
                vmax[r] = fmaxf(vmax[r], sqiA[mt][r] + sqjA[nt] - 2.0f * acc[mt][nt][r]);
        #pragma unroll
        for (int r = 0; r < 4; ++r) {
            float v = vmax[r];
            v = fmaxf(v, __shfl_xor(v, 1, 64));
            v = fmaxf(v, __shfl_xor(v, 2, 64));
            v = fmaxf(v, __shfl_xor(v, 4, 64));
            v = fmaxf(v, __shfl_xor(v, 8, 64));
            if ((lane & 15) == 0) {
                const float d = sqrtf(fmaxf(v, 1e-12f));
                atomicMax((unsigned int*)&m[base + I0 + wr * 64 + mt * 16 + (lane >> 4) * 4 + r],
                          __float_as_uint(d));
            }
        }
    }

    // col-max -> m[J-cols] (off-diagonal tiles only; branch is block-uniform)
    if (I0 != J0) {
        #pragma unroll
        for (int nt = 0; nt < 4; ++nt) {
            float cm = -1e30f;
            #pragma unroll
            for (int mt = 0; mt < 4; ++mt)
                #pragma unroll
                for (int r = 0; r < 4; ++r)
                    cm = fmaxf(cm, sqiA[mt][r] + sqjA[nt] - 2.0f * acc[mt][nt][r]);
            cm = fmaxf(cm, __shfl_xor(cm, 16, 64));
            cm = fmaxf(cm, __shfl_xor(cm, 32, 64));
            if ((lane >> 4) == 0) {
                const float d = sqrtf(fmaxf(cm, 1e-12f));
                atomicMax((unsigned int*)&m[base + J0 + wc * 64 + nt * 16 + (lane & 15)],
                          __float_as_uint(d));
            }
        }
    }
}

extern "C" void kernel_launch(void* const* d_in, const int* in_sizes, int n_in,
                              void* d_out, int out_size, void* d_ws, size_t ws_size,
                              hipStream_t stream)
{
    const float* x     = (const float*)d_in[0];
    const float* gamma = (const float*)d_in[1];
    const float* beta  = (const float*)d_in[2];
    const float* w1    = (const float*)d_in[3];
    const float* b1    = (const float*)d_in[4];
    const float* w2    = (const float*)d_in[5];
    const float* b2    = (const float*)d_in[6];
    const float* w3    = (const float*)d_in[7];
    const float* b3    = (const float*)d_in[8];
    const float* w4    = (const float*)d_in[9];
    const float* b4    = (const float*)d_in[10];
    float* out = (float*)d_out;
    float* ws  = (float*)d_ws;

    // ws: avgx[12288] mbuf[16384] s1[768] sq[16384] | w1T..w4T fp16 | P0,P1 fp16
    // (avgx+mbuf+s1 adjacent -> ONE memset clears all three)
    float* avgx = ws;
    float* mbuf = ws + 12288;
    float* s1   = mbuf + 16384;
    float* sq   = s1 + 768;
    __half* w1T = (__half*)(sq + 16384);
    __half* w2T = w1T + (size_t)1536 * 768;
    __half* w3T = w2T + (size_t)768 * 768;
    __half* w4T = w3T + (size_t)768 * 768;
    __half* P0  = w4T + (size_t)768 * 768;            // m1H, later h4H
    __half* P1  = P0 + (size_t)BNR * DIM;             // h3H
    // d_out hosts the two L1-only fp16 operands (dead before L4 writes out)
    __half* Ah  = (__half*)d_out;
    __half* xh  = Ah + (size_t)BNR * DIM;

    hipMemsetAsync(ws, 0, (12288 + 16384 + 768) * sizeof(float), stream);
    wconv<<<dim3(12, 24), 256, 0, stream>>>(w1, w1T, 1536, 768);
    wconv3<<<dim3(12, 12, 3), 256, 0, stream>>>(w2, w3, w4, w2T, w3T, w4T);
    colsum_w1b<<<dim3(3, 12), 256, 0, stream>>>(w1, s1);
    avg_kernel<<<dim3(3, NBATCH, 8), 256, 0, stream>>>(x, avgx);
    ln_sig_kernel<<<BNR / 4, 256, 0, stream>>>(x, gamma, beta, avgx, Ah, xh, sq);
    dist16<<<dim3(NBATCH, 36), 256, 0, stream>>>(Ah, sq, mbuf);
    // L1: m1 = gelu(cat @ w1 + b1) = gelu(A@w1a + x@w1b + m[row]*s1[col] + b1)
    gemm16<1536, true, 0><<<dim3(128, 6), 512, 0, stream>>>(
        Ah, xh, w1T, b1, nullptr, nullptr, mbuf, s1, P0, nullptr);
    // L2: h3 = m1 * x * gelu(m1 @ w2 + b2)
    gemm16<768, false, 1><<<dim3(128, 6), 512, 0, stream>>>(
        P0, nullptr, w2T, b2, x, P0, nullptr, nullptr, P1, nullptr);
    // L3: h4 = x * gelu(h3 @ w3 + b3)
    gemm16<768, false, 2><<<dim3(128, 6), 512, 0, stream>>>(
        P1, nullptr, w3T, b3, x, nullptr, nullptr, nullptr, P0, nullptr);
    // L4: out = gelu(h4 @ w4 + b4)
    gemm16<768, false, 3><<<dim3(128, 6), 512, 0, stream>>>(
        P0, nullptr, w4T, b4, x, nullptr, nullptr, nullptr, nullptr, out);
}

// Round 9
// 326.151 us; speedup vs baseline: 1.0499x; 1.0499x over previous
//
#include <hip/hip_runtime.h>
#include <hip/hip_fp16.h>
#include <math.h>

#define DIM 768
#define NTOK 1024
#define NBATCH 16
#define BNR (NBATCH * NTOK)   // 16384 rows

typedef _Float16 f16x8 __attribute__((ext_vector_type(8)));
typedef float f32x4 __attribute__((ext_vector_type(4)));

// async global->LDS, 16B per lane, LDS dest = wave-uniform base + lane*16
__device__ __forceinline__ void gl2lds16(const void* g, void* l) {
    __builtin_amdgcn_global_load_lds(
        (const __attribute__((address_space(1))) void*)g,
        (__attribute__((address_space(3))) void*)l, 16, 0, 0);
}

// branch-free exact-gelu: erf via Abramowitz-Stegun 7.1.26 (|abs err| <= 1.5e-7)
__device__ __forceinline__ float gelu_fast(float z) {
    const float s = z * 0.70710678118654752f;
    const float ax = fabsf(s);
    const float t = __builtin_amdgcn_rcpf(1.0f + 0.3275911f * ax);
    const float poly = t * (0.254829592f + t * (-0.284496736f +
                       t * (1.421413741f + t * (-1.453152027f + t * 1.061405429f))));
    const float e = __expf(-ax * ax);
    float erfv = 1.0f - poly * e;
    erfv = copysignf(erfv, s);
    return 0.5f * z * (1.0f + erfv);
}

// avg over tokens, split 8-way over the token axis for parallelism
__global__ __launch_bounds__(256) void avg_kernel(const float* __restrict__ x,
                                                  float* __restrict__ avgx) {
    const int d = blockIdx.x * 256 + threadIdx.x;
    const int b = blockIdx.y;
    const int n0 = blockIdx.z * 128;
    const float* xp = x + (size_t)b * NTOK * DIM + (size_t)n0 * DIM + d;
    float s = 0.0f;
    for (int n = 0; n < 128; ++n) s += xp[(size_t)n * DIM];
    atomicAdd(&avgx[b * DIM + d], s * (1.0f / NTOK));
}

// s1[col] = sum over k of w1[768+k][col]  (rank-1 term for the (x+m) half of L1)
__global__ __launch_bounds__(256) void colsum_w1b(const float* __restrict__ w1,
                                                  float* __restrict__ s1) {
    const int col = blockIdx.x * 256 + threadIdx.x;   // 3 col-blocks
    const int r0 = 768 + blockIdx.y * 64;             // 12 row-chunks
    float s = 0.0f;
    #pragma unroll 8
    for (int r = 0; r < 64; ++r) s += w1[(size_t)(r0 + r) * 768 + col];
    atomicAdd(&s1[col], s);
}

// LN -> sigmoid -> A = avg_x*sig (fp16), plus xh = fp16(x); wave-per-row, no barriers.
// sq computed from fp16-rounded A (consistent with what dist16 consumes).
__global__ __launch_bounds__(256) void ln_sig_kernel(
    const float* __restrict__ x, const float* __restrict__ gamma,
    const float* __restrict__ beta, const float* __restrict__ avgx,
    __half* __restrict__ Ah, __half* __restrict__ xh, float* __restrict__ sq)
{
    const int wv = threadIdx.x >> 6, lane = threadIdx.x & 63;
    const int row = blockIdx.x * 4 + wv;
    const int b = row >> 10;
    const float* xr = x + (size_t)row * DIM;
    float4 v[3];
    #pragma unroll
    for (int i = 0; i < 3; ++i) v[i] = *(const float4*)&xr[i * 256 + lane * 4];
    float s = v[0].x + v[0].y + v[0].z + v[0].w
            + v[1].x + v[1].y + v[1].z + v[1].w
            + v[2].x + v[2].y + v[2].z + v[2].w;
    #pragma unroll
    for (int o = 32; o > 0; o >>= 1) s += __shfl_xor(s, o, 64);
    const float mu = s * (1.0f / DIM);
    float ss = 0.0f;
    #pragma unroll
    for (int i = 0; i < 3; ++i) {
        const float dx0 = v[i].x - mu, dx1 = v[i].y - mu, dx2 = v[i].z - mu, dx3 = v[i].w - mu;
        ss += dx0 * dx0 + dx1 * dx1 + dx2 * dx2 + dx3 * dx3;
    }
    #pragma unroll
    for (int o = 32; o > 0; o >>= 1) ss += __shfl_xor(ss, o, 64);
    const float rstd = rsqrtf(ss * (1.0f / DIM) + 1e-5f);
    float qs = 0.0f;
    #pragma unroll
    for (int i = 0; i < 3; ++i) {
        const int d0 = i * 256 + lane * 4;
        const float4 g4 = *(const float4*)&gamma[d0];
        const float4 b4 = *(const float4*)&beta[d0];
        const float4 a4 = *(const float4*)&avgx[b * DIM + d0];
        ushort4 pa, px;
        const float xv[4] = {v[i].x, v[i].y, v[i].z, v[i].w};
        const float gv[4] = {g4.x, g4.y, g4.z, g4.w};
        const float bv[4] = {b4.x, b4.y, b4.z, b4.w};
        const float av[4] = {a4.x, a4.y, a4.z, a4.w};
        unsigned short pav[4], pxv[4];
        #pragma unroll
        for (int j = 0; j < 4; ++j) {
            const float ln = (xv[j] - mu) * rstd * gv[j] + bv[j];
            const float sg = 1.0f / (1.0f + expf(-ln));
            const float a = av[j] * sg;
            const __half h = __float2half(a);
            const float ar = __half2float(h);
            qs += ar * ar;
            pav[j] = __half_as_ushort(h);
            pxv[j] = __half_as_ushort(__float2half(xv[j]));
        }
        pa.x = pav[0]; pa.y = pav[1]; pa.z = pav[2]; pa.w = pav[3];
        px.x = pxv[0]; px.y = pxv[1]; px.z = pxv[2]; px.w = pxv[3];
        *(ushort4*)&Ah[(size_t)row * DIM + d0] = pa;
        *(ushort4*)&xh[(size_t)row * DIM + d0] = px;
    }
    #pragma unroll
    for (int o = 32; o > 0; o >>= 1) qs += __shfl_xor(qs, o, 64);
    if (lane == 0) sq[row] = qs;
}

// fp32 [K][N] -> fp16 [N][K] tiled transpose (shared body)
__device__ __forceinline__ void wconv_body(const float* __restrict__ w,
                                           __half* __restrict__ wT, int K, int N,
                                           int bx, int by)
{
    __shared__ float t[64][65];
    const int k0 = by * 64, n0 = bx * 64;
    const int tid = threadIdx.x;
    const int r = tid >> 4, c4 = (tid & 15) * 4;
    #pragma unroll
    for (int p = 0; p < 4; ++p) {
        const int rr = p * 16 + r;
        const float4 v = *(const float4*)&w[(size_t)(k0 + rr) * N + n0 + c4];
        t[rr][c4] = v.x; t[rr][c4 + 1] = v.y; t[rr][c4 + 2] = v.z; t[rr][c4 + 3] = v.w;
    }
    __syncthreads();
    #pragma unroll
    for (int p = 0; p < 4; ++p) {
        const int nn = p * 16 + r;
        ushort4 pk;
        pk.x = __half_as_ushort(__float2half(t[c4 + 0][nn]));
        pk.y = __half_as_ushort(__float2half(t[c4 + 1][nn]));
        pk.z = __half_as_ushort(__float2half(t[c4 + 2][nn]));
        pk.w = __half_as_ushort(__float2half(t[c4 + 3][nn]));
        *(ushort4*)&wT[(size_t)(n0 + nn) * K + k0 + c4] = pk;
    }
}

__global__ __launch_bounds__(256) void wconv(const float* __restrict__ w,
                                             __half* __restrict__ wT, int K, int N)
{
    wconv_body(w, wT, K, N, blockIdx.x, blockIdx.y);
}

// batched 768x768 transposes for w2/w3/w4 (one dispatch instead of three)
__global__ __launch_bounds__(256) void wconv3(const float* __restrict__ w2,
                                              const float* __restrict__ w3,
                                              const float* __restrict__ w4,
                                              __half* __restrict__ t2,
                                              __half* __restrict__ t3,
                                              __half* __restrict__ t4)
{
    const float* w = (blockIdx.z == 0) ? w2 : (blockIdx.z == 1) ? w3 : w4;
    __half* wT = (blockIdx.z == 0) ? t2 : (blockIdx.z == 1) ? t3 : t4;
    wconv_body(w, wT, 768, 768, blockIdx.x, blockIdx.y);
}

// ---- MFMA fp16 GEMM, 256x192 tile, BK=64, 8 waves, dbuf, 1 block/CU ----
// The 2-phase 128x128/BK32 family plateaued at ~55-58us across depth (R1,R8), width
// (R3,R7), conflicts (R2), XCD (R6): its ~600cy iteration is SHORTER than the
// ~600-900cy staging latency, so every barrier exposes the difference. Fix: grow the
// iteration past the latency. 256x192xBK64 -> per CU-iter ~1860cy matrix + ~1920cy
// LDS (balanced pipes); depth-1 prefetch gets a full ~1900cy in flight -> plain
// __syncthreads dbuf suffices (no asm ring). LDS 112KB -> exactly 1 block/CU;
// grid 64x4 = 256 blocks = exactly 1 per CU (zero remainder). 8 waves as 4x2,
// per-wave output 64x96 (acc 4x6), ~1.5x less LDS-read amplification than 128x128.
// LDS swizzle (rows now 64 halves = 8 octs): phys-oct = log-oct ^ (row&7).
//  - staging: lane l of an 8-row slab (slab base = o*64+w*8, always ==0 mod 8):
//    row = base+(l>>3), writes phys-oct l&7, fetches global oct (l&7)^((l>>3)&7)
//    -> 8 lanes fetch a permutation of 8 consecutive 16B units = 128B coalesced.
//  - frag read af[mt]@kh: row = wr*64+mt*16+(lane&15), log-oct = kh*4+(lane>>4),
//    addr(halves) = row*64 + (log^(row&7))*8 -> bank-group = phys-oct, 16 rows
//    cycle row&7 twice -> 2-way aliasing = free (same proof class as the verified
//    128-tile swizzle that took SQ_LDS_BANK_CONFLICT 4.72M -> 0).
// EPI 0: m1=gelu(z + m[row]*s1[col])->fp16 ; 1: h3=m1h*x*gelu(z)->fp16 ;
// EPI 2: h4=x*gelu(z)->fp16 ; 3: out=gelu(z)->fp32
template<int K, bool CAT, int EPI>
__global__ __launch_bounds__(512, 2) void gemm256(
    const __half* __restrict__ A0, const __half* __restrict__ A1,
    const __half* __restrict__ BT, const float* __restrict__ bias,
    const float* __restrict__ xin, const __half* __restrict__ m1h,
    const float* __restrict__ mv, const float* __restrict__ sv,
    __half* __restrict__ outH, float* __restrict__ outF)
{
    __shared__ _Float16 As[2][256 * 64];
    __shared__ _Float16 Bs[2][192 * 64];
    const int tid = threadIdx.x;
    const int w = tid >> 6, lane = tid & 63;
    const int wu = __builtin_amdgcn_readfirstlane(w);
    const int wr = w >> 1, wc = w & 1;          // wave -> 64-row x 96-col quadrant
    const int R0 = blockIdx.x * 256, J0 = blockIdx.y * 192;
    constexpr int rs = CAT ? DIM : K;           // A row stride (halves)
    const int srow = lane >> 3;                 // row within 8-row slab
    const int soct = ((lane & 7) ^ ((lane >> 3) & 7)) * 8;   // fetched oct (halves)
    constexpr int NT = K / 64;

    f32x4 acc[4][6];
    #pragma unroll
    for (int mt = 0; mt < 4; ++mt)
        #pragma unroll
        for (int nt = 0; nt < 6; ++nt) {
            f32x4 z = {0.0f, 0.0f, 0.0f, 0.0f};
            acc[mt][nt] = z;
        }

    auto stage = [&](int buf, int k0) {
        const __half* Ab = (CAT && k0 >= DIM) ? (A1 + (k0 - DIM)) : (A0 + k0);
        #pragma unroll
        for (int o = 0; o < 4; ++o) {           // A: 4 slabs x 64 rows
            const int r = o * 64 + w * 8 + srow;
            const int ru = o * 64 + wu * 8;
            gl2lds16(Ab + (size_t)(R0 + r) * rs + soct, &As[buf][ru * 64]);
        }
        #pragma unroll
        for (int o = 0; o < 3; ++o) {           // B: 3 slabs x 64 rows
            const int r = o * 64 + w * 8 + srow;
            const int ru = o * 64 + wu * 8;
            gl2lds16(BT + (size_t)(J0 + r) * K + k0 + soct, &Bs[buf][ru * 64]);
        }
    };

    stage(0, 0);
    __syncthreads();
    #pragma unroll 2
    for (int kt = 0; kt < NT; ++kt) {
        const int cur = kt & 1;
        if (kt + 1 < NT) stage(cur ^ 1, (kt + 1) * 64);
        #pragma unroll
        for (int kh = 0; kh < 2; ++kh) {
            f16x8 af[4], bf[6];
            #pragma unroll
            for (int mt = 0; mt < 4; ++mt) {
                const int row = wr * 64 + mt * 16 + (lane & 15);
                const int oct = (kh * 4 + (lane >> 4)) ^ (row & 7);
                af[mt] = *(const f16x8*)&As[cur][row * 64 + oct * 8];
            }
            #pragma unroll
            for (int nt = 0; nt < 6; ++nt) {
                const int row = wc * 96 + nt * 16 + (lane & 15);
                const int oct = (kh * 4 + (lane >> 4)) ^ (row & 7);
                bf[nt] = *(const f16x8*)&Bs[cur][row * 64 + oct * 8];
            }
            #pragma unroll
            for (int mt = 0; mt < 4; ++mt)
                #pragma unroll
                for (int nt = 0; nt < 6; ++nt)
                    acc[mt][nt] = __builtin_amdgcn_mfma_f32_16x16x32_f16(af[mt], bf[nt], acc[mt][nt], 0, 0, 0);
        }
        __syncthreads();
    }

    // C/D layout: col = lane&15, row = (lane>>4)*4 + reg
    #pragma unroll
    for (int mt = 0; mt < 4; ++mt) {
        float mrow[4];
        if constexpr (EPI == 0) {
            #pragma unroll
            for (int r = 0; r < 4; ++r)
                mrow[r] = mv[R0 + wr * 64 + mt * 16 + (lane >> 4) * 4 + r];
        }
        #pragma unroll
        for (int nt = 0; nt < 6; ++nt) {
            const int col = J0 + wc * 96 + nt * 16 + (lane & 15);
            const float bv = bias[col];
            float s1c = 0.0f;
            if constexpr (EPI == 0) s1c = sv[col];
            #pragma unroll
            for (int r = 0; r < 4; ++r) {
                const int row = R0 + wr * 64 + mt * 16 + (lane >> 4) * 4 + r;
                const size_t off = (size_t)row * DIM + col;
                if (EPI == 0) {
                    const float g = gelu_fast(acc[mt][nt][r] + bv + mrow[r] * s1c);
                    outH[off] = __float2half(g);
                } else if (EPI == 1) {
                    const float g = gelu_fast(acc[mt][nt][r] + bv);
                    outH[off] = __float2half(__half2float(m1h[off]) * xin[off] * g);
                } else if (EPI == 2) {
                    const float g = gelu_fast(acc[mt][nt][r] + bv);
                    outH[off] = __float2half(xin[off] * g);
                } else {
                    outF[off] = gelu_fast(acc[mt][nt][r] + bv);
                }
            }
        }
    }
}

// dist row-max over UPPER-TRIANGLE tiles only (dist is symmetric): 36 of 64
// 128x128 tiles per batch. Off-diagonal tiles contribute the row-max to m[I-rows]
// AND the col-max to m[J-cols]; diagonal tiles are full, row-max suffices.
// (Reverted to the verified R7 form: plain dbuf + __syncthreads, 4 waves.)
// atomicMax on positive floats as uints is order-preserving; max commutes with sqrt.
__global__ __launch_bounds__(256, 4) void dist16(const __half* __restrict__ Ah,
                                                 const float* __restrict__ sq,
                                                 float* __restrict__ m)
{
    __shared__ _Float16 As[2][128 * 32];
    __shared__ _Float16 Bs[2][128 * 32];
    const int tid = threadIdx.x;
    const int w = tid >> 6, lane = tid & 63;
    const int wu = __builtin_amdgcn_readfirstlane(w);
    const int wr = w >> 1, wc = w & 1;
    const int base = blockIdx.x * NTOK;
    // decode upper-triangle tile id -> (ty, tz), ty<=tz, 8x8 tile grid
    int t = blockIdx.y, ty = 0;
    while (t >= 8 - ty) { t -= 8 - ty; ++ty; }
    const int tz = ty + t;
    const int I0 = ty * 128, J0 = tz * 128;
    const int srow = lane >> 2;
    const int sk8 = (((lane & 3) ^ ((lane >> 3) & 3))) * 8;
    const int fx = ((lane >> 4) ^ ((lane >> 1) & 3)) * 8;
    constexpr int NT = DIM / 32;

    f32x4 acc[4][4];
    #pragma unroll
    for (int mt = 0; mt < 4; ++mt)
        #pragma unroll
        for (int nt = 0; nt < 4; ++nt) {
            f32x4 z = {0.0f, 0.0f, 0.0f, 0.0f};
            acc[mt][nt] = z;
        }

    auto stage = [&](int buf, int k0) {
        #pragma unroll
        for (int i = 0; i < 2; ++i) {
            const int rbase = i * 64 + w * 16;
            const int rbu = i * 64 + wu * 16;
            gl2lds16(Ah + (size_t)(base + I0 + rbase + srow) * DIM + k0 + sk8, &As[buf][rbu * 32]);
            gl2lds16(Ah + (size_t)(base + J0 + rbase + srow) * DIM + k0 + sk8, &Bs[buf][rbu * 32]);
        }
    };

    stage(0, 0);
    __syncthreads();
    #pragma unroll 2
    for (int kt = 0; kt < NT; ++kt) {
        const int cur = kt & 1;
        if (kt + 1 < NT) stage(cur ^ 1, (kt + 1) * 32);
        f16x8 af[4], bf[4];
        #pragma unroll
        for (int mt = 0; mt < 4; ++mt)
            af[mt] = *(const f16x8*)&As[cur][(wr * 64 + mt * 16 + (lane & 15)) * 32 + fx];
        #pragma unroll
        for (int nt = 0; nt < 4; ++nt)
            bf[nt] = *(const f16x8*)&Bs[cur][(wc * 64 + nt * 16 + (lane & 15)) * 32 + fx];
        #pragma unroll
        for (int mt = 0; mt < 4; ++mt)
            #pragma unroll
            for (int nt = 0; nt < 4; ++nt)
                acc[mt][nt] = __builtin_amdgcn_mfma_f32_16x16x32_f16(af[mt], bf[nt], acc[mt][nt], 0, 0, 0);
        __syncthreads();
    }

    float sqiA[4][4];
    #pragma unroll
    for (int mt = 0; mt < 4; ++mt)
        #pragma unroll
        for (int r = 0; r < 4; ++r)
            sqiA[mt][r] = sq[base + I0 + wr * 64 + mt * 16 + (lane >> 4) * 4 + r];
    float sqjA[4];
    #pragma unroll
    for (int nt = 0; nt < 4; ++nt)
        sqjA[nt] = sq[base + J0 + wc * 64 + nt * 16 + (lane & 15)];

    // row-max -> m[I-rows]
    #pragma unroll
    for (int mt = 0; mt < 4; ++mt) {
        float vmax[4] = {-1e30f, -1e30f, -1e30f, -1e30f};
        #pragma unroll
        for (int nt = 0; nt < 4; ++nt)
            #pragma unroll
            for (int r = 0; r < 4; ++r)
                vmax[r] = fmaxf(vmax[r], sqiA[mt][r] + sqjA[nt] - 2.0f * acc[mt][nt][r]);
        #pragma unroll
        for (int r = 0; r < 4; ++r) {
            float v = vmax[r];
            v = fmaxf(v, __shfl_xor(v, 1, 64));
            v = fmaxf(v, __shfl_xor(v, 2, 64));
            v = fmaxf(v, __shfl_xor(v, 4, 64));
            v = fmaxf(v, __shfl_xor(v, 8, 64));
            if ((lane & 15) == 0) {
                const float d = sqrtf(fmaxf(v, 1e-12f));
                atomicMax((unsigned int*)&m[base + I0 + wr * 64 + mt * 16 + (lane >> 4) * 4 + r],
                          __float_as_uint(d));
            }
        }
    }

    // col-max -> m[J-cols] (off-diagonal tiles only; branch is block-uniform)
    if (I0 != J0) {
        #pragma unroll
        for (int nt = 0; nt < 4; ++nt) {
            float cm = -1e30f;
            #pragma unroll
            for (int mt = 0; mt < 4; ++mt)
                #pragma unroll
                for (int r = 0; r < 4; ++r)
                    cm = fmaxf(cm, sqiA[mt][r] + sqjA[nt] - 2.0f * acc[mt][nt][r]);
            cm = fmaxf(cm, __shfl_xor(cm, 16, 64));
            cm = fmaxf(cm, __shfl_xor(cm, 32, 64));
            if ((lane >> 4) == 0) {
                const float d = sqrtf(fmaxf(cm, 1e-12f));
                atomicMax((unsigned int*)&m[base + J0 + wc * 64 + nt * 16 + (lane & 15)],
                          __float_as_uint(d));
            }
        }
    }
}

extern "C" void kernel_launch(void* const* d_in, const int* in_sizes, int n_in,
                              void* d_out, int out_size, void* d_ws, size_t ws_size,
                              hipStream_t stream)
{
    const float* x     = (const float*)d_in[0];
    const float* gamma = (const float*)d_in[1];
    const float* beta  = (const float*)d_in[2];
    const float* w1    = (const float*)d_in[3];
    const float* b1    = (const float*)d_in[4];
    const float* w2    = (const float*)d_in[5];
    const float* b2    = (const float*)d_in[6];
    const float* w3    = (const float*)d_in[7];
    const float* b3    = (const float*)d_in[8];
    const float* w4    = (const float*)d_in[9];
    const float* b4    = (const float*)d_in[10];
    float* out = (float*)d_out;
    float* ws  = (float*)d_ws;

    // ws: avgx[12288] mbuf[16384] s1[768] sq[16384] | w1T..w4T fp16 | P0,P1 fp16
    // (avgx+mbuf+s1 adjacent -> ONE memset clears all three)
    float* avgx = ws;
    float* mbuf = ws + 12288;
    float* s1   = mbuf + 16384;
    float* sq   = s1 + 768;
    __half* w1T = (__half*)(sq + 16384);
    __half* w2T = w1T + (size_t)1536 * 768;
    __half* w3T = w2T + (size_t)768 * 768;
    __half* w4T = w3T + (size_t)768 * 768;
    __half* P0  = w4T + (size_t)768 * 768;            // m1H, later h4H
    __half* P1  = P0 + (size_t)BNR * DIM;             // h3H
    // d_out hosts the two L1-only fp16 operands (dead before L4 writes out)
    __half* Ah  = (__half*)d_out;
    __half* xh  = Ah + (size_t)BNR * DIM;

    hipMemsetAsync(ws, 0, (12288 + 16384 + 768) * sizeof(float), stream);
    wconv<<<dim3(12, 24), 256, 0, stream>>>(w1, w1T, 1536, 768);
    wconv3<<<dim3(12, 12, 3), 256, 0, stream>>>(w2, w3, w4, w2T, w3T, w4T);
    colsum_w1b<<<dim3(3, 12), 256, 0, stream>>>(w1, s1);
    avg_kernel<<<dim3(3, NBATCH, 8), 256, 0, stream>>>(x, avgx);
    ln_sig_kernel<<<BNR / 4, 256, 0, stream>>>(x, gamma, beta, avgx, Ah, xh, sq);
    dist16<<<dim3(NBATCH, 36), 256, 0, stream>>>(Ah, sq, mbuf);
    // L1: m1 = gelu(cat @ w1 + b1) = gelu(A@w1a + x@w1b + m[row]*s1[col] + b1)
    gemm256<1536, true, 0><<<dim3(64, 4), 512, 0, stream>>>(
        Ah, xh, w1T, b1, nullptr, nullptr, mbuf, s1, P0, nullptr);
    // L2: h3 = m1 * x * gelu(m1 @ w2 + b2)
    gemm256<768, false, 1><<<dim3(64, 4), 512, 0, stream>>>(
        P0, nullptr, w2T, b2, x, P0, nullptr, nullptr, P1, nullptr);
    // L3: h4 = x * gelu(h3 @ w3 + b3)
    gemm256<768, false, 2><<<dim3(64, 4), 512, 0, stream>>>(
        P1, nullptr, w3T, b3, x, nullptr, nullptr, nullptr, P0, nullptr);
    // L4: out = gelu(h4 @ w4 + b4)
    gemm256<768, false, 3><<<dim3(64, 4), 512, 0, stream>>>(
        P0, nullptr, w4T, b4, x, nullptr, nullptr, nullptr, nullptr, out);
}